// Round 7
// baseline (218.789 us; speedup 1.0000x reference)
//
#include <hip/hip_runtime.h>

// B-spline 3D field, 2M points, 128^3 x 3 f32 grid.
// Round 7:
//  - sort side: 512 blocks x 1024 thr (2 blocks/CU, 32 waves) for hist and
//    scatter; one vectorized iter/thread. hist stored u16 to keep ws at the
//    known-good 36.2 MB.
//  - all passes: replace fp32 divides with (x+1)*62.5f (exact inverse).
//  - eval: packed fp32 (v_pk_fma_f32) via float2 ext-vector accumulators.
//    (Round-6 showed LDS conflicts are statistical -- padding didn't move
//    them -- so the eval lever is VALU issue count.)

#define NBINS 4096   // 16x16x16 bins of 8^3 cells
#define NBLK  512    // hist/scatter chunks
#define W4STRIDE 25  // float4 per brick row (padded; 24 used)

typedef float v2f __attribute__((ext_vector_type(2)));

__device__ __forceinline__ void bspline_w(float u, float& w0, float& w1,
                                          float& w2, float& w3) {
    const float u2 = u * u;
    const float u3 = u2 * u;
    const float t  = 1.0f - u;
    w0 = t * t * t * (1.0f / 6.0f);
    w1 = (3.0f * u3 - 6.0f * u2 + 4.0f) * (1.0f / 6.0f);
    w2 = (-3.0f * u3 + 3.0f * u2 + 3.0f * u + 1.0f) * (1.0f / 6.0f);
    w3 = u3 * (1.0f / 6.0f);
}

// (x - ox - dx) == x + 1 algebraically; 1/dx == 62.5 exactly.
__device__ __forceinline__ int point_bin(float x, float y, float z) {
    const int ix = (int)floorf((x + 1.0f) * 62.5f);
    const int iy = (int)floorf((y + 1.0f) * 62.5f);
    const int iz = (int)floorf((z + 1.0f) * 62.5f);
    const int bx = min(max(ix, 0), 127) >> 3;
    const int by = min(max(iy, 0), 127) >> 3;
    const int bz = min(max(iz, 0), 127) >> 3;
    return (bx << 8) | (by << 4) | bz;
}

// ---- pass A: per-block histograms, vectorized, u16 out ----
__global__ __launch_bounds__(1024) void hist_kernel(
    const float* __restrict__ xs, const float* __restrict__ ys,
    const float* __restrict__ zs, unsigned short* __restrict__ hist,
    int n, int chunk) {
    __shared__ unsigned h[NBINS];
    for (int j = threadIdx.x; j < NBINS; j += 1024) h[j] = 0;
    __syncthreads();
    const int b = blockIdx.x;
    const int lo = b * chunk;  // chunk % 4 == 0
    const int hi = min(n, lo + chunk);
    for (int base = lo + threadIdx.x * 4; base < hi; base += 1024 * 4) {
        if (base + 4 <= hi) {
            const float4 x4 = *reinterpret_cast<const float4*>(xs + base);
            const float4 y4 = *reinterpret_cast<const float4*>(ys + base);
            const float4 z4 = *reinterpret_cast<const float4*>(zs + base);
            atomicAdd(&h[point_bin(x4.x, y4.x, z4.x)], 1u);
            atomicAdd(&h[point_bin(x4.y, y4.y, z4.y)], 1u);
            atomicAdd(&h[point_bin(x4.z, y4.z, z4.z)], 1u);
            atomicAdd(&h[point_bin(x4.w, y4.w, z4.w)], 1u);
        } else {
            for (int i = base; i < hi; ++i)
                atomicAdd(&h[point_bin(xs[i], ys[i], zs[i])], 1u);
        }
    }
    __syncthreads();
    for (int j = threadIdx.x; j < NBINS; j += 1024)
        hist[b * NBINS + j] = (unsigned short)h[j];
}

// ---- pass B: relative column scan (u16 in/out), totals u32 ----
__global__ __launch_bounds__(256) void colscan_kernel(
    unsigned short* __restrict__ hist, unsigned* __restrict__ total) {
    const int j = blockIdx.x * 256 + threadIdx.x;
    unsigned run = 0;
#pragma unroll 16
    for (int b = 0; b < NBLK; ++b) {
        const unsigned c = hist[b * NBINS + j];
        hist[b * NBINS + j] = (unsigned short)run;
        run += c;
    }
    total[j] = run;
}

// ---- pass C: exclusive scan of totals -> binbase ----
__global__ __launch_bounds__(1024) void scan_kernel(
    const unsigned* __restrict__ total, unsigned* __restrict__ binbase) {
    __shared__ unsigned sdata[1024];
    const int t = threadIdx.x;
    const unsigned v0 = total[4 * t + 0];
    const unsigned v1 = total[4 * t + 1];
    const unsigned v2 = total[4 * t + 2];
    const unsigned v3 = total[4 * t + 3];
    sdata[t] = v0 + v1 + v2 + v3;
    __syncthreads();
    for (int off = 1; off < 1024; off <<= 1) {
        unsigned x = (t >= off) ? sdata[t - off] : 0u;
        __syncthreads();
        sdata[t] += x;
        __syncthreads();
    }
    const unsigned ex = (t > 0) ? sdata[t - 1] : 0u;
    binbase[4 * t + 0] = ex;
    binbase[4 * t + 1] = ex + v0;
    binbase[4 * t + 2] = ex + v0 + v1;
    binbase[4 * t + 3] = ex + v0 + v1 + v2;
}

// ---- pass D: scatter records, LDS cursors, vectorized ----
__global__ __launch_bounds__(1024) void scatter_kernel(
    const float* __restrict__ xs, const float* __restrict__ ys,
    const float* __restrict__ zs, const unsigned short* __restrict__ hist,
    const unsigned* __restrict__ binbase, float4* __restrict__ rec,
    int n, int chunk) {
    __shared__ unsigned off[NBINS];
    const int b = blockIdx.x;
    for (int j = threadIdx.x; j < NBINS; j += 1024)
        off[j] = (unsigned)hist[b * NBINS + j] + binbase[j];
    __syncthreads();
    const int lo = b * chunk;
    const int hi = min(n, lo + chunk);
    for (int base = lo + threadIdx.x * 4; base < hi; base += 1024 * 4) {
        if (base + 4 <= hi) {
            const float4 x4 = *reinterpret_cast<const float4*>(xs + base);
            const float4 y4 = *reinterpret_cast<const float4*>(ys + base);
            const float4 z4 = *reinterpret_cast<const float4*>(zs + base);
            unsigned p;
            p = atomicAdd(&off[point_bin(x4.x, y4.x, z4.x)], 1u);
            rec[p] = make_float4(x4.x, y4.x, z4.x, __int_as_float(base + 0));
            p = atomicAdd(&off[point_bin(x4.y, y4.y, z4.y)], 1u);
            rec[p] = make_float4(x4.y, y4.y, z4.y, __int_as_float(base + 1));
            p = atomicAdd(&off[point_bin(x4.z, y4.z, z4.z)], 1u);
            rec[p] = make_float4(x4.z, y4.z, z4.z, __int_as_float(base + 2));
            p = atomicAdd(&off[point_bin(x4.w, y4.w, z4.w)], 1u);
            rec[p] = make_float4(x4.w, y4.w, z4.w, __int_as_float(base + 3));
        } else {
            for (int i = base; i < hi; ++i) {
                const float x = xs[i], y = ys[i], z = zs[i];
                const unsigned p = atomicAdd(&off[point_bin(x, y, z)], 1u);
                rec[p] = make_float4(x, y, z, __int_as_float(i));
            }
        }
    }
}

// ---- pass E: evaluate, one block per bin, packed fp32 math ----
__global__ __launch_bounds__(512, 6) void eval_kernel(
    const float4* __restrict__ rec, const unsigned* __restrict__ binbase,
    const unsigned* __restrict__ total, const float* __restrict__ phi,
    float* __restrict__ out) {
    const int bin = blockIdx.x;
    const unsigned cnt = total[bin];
    if (cnt == 0) return;
    const unsigned start = binbase[bin];

    const int gx0 = ((bin >> 8) & 15) << 3;
    const int gy0 = ((bin >> 4) & 15) << 3;
    const int gz0 = (bin & 15) << 3;

    __shared__ float raw[31 * 36];         // 4464 B rolling stage
    __shared__ float4 W4[121 * W4STRIDE];  // 48400 B  (total 52.9 KB)

    for (int r0 = 0; r0 < 121; r0 += 31) {
        const int nr = min(31, 121 - r0);
        if (gz0 <= 112) {
            for (int p = threadIdx.x; p < nr * 9; p += 512) {
                const int rr = p / 9, q = p - rr * 9;
                const int row = r0 + rr;
                const int lx = row / 11, ly = row - lx * 11;
                const int gx = min(gx0 + lx, 127);
                const int gy = min(gy0 + ly, 127);
                const float* src =
                    phi + (size_t)((gx * 128 + gy) * 128 + gz0) * 3 + q * 4;
                *reinterpret_cast<float4*>(&raw[rr * 36 + q * 4]) =
                    *reinterpret_cast<const float4*>(src);
            }
        } else {
            for (int p = threadIdx.x; p < nr * 11; p += 512) {
                const int rr = p / 11, zz = p - rr * 11;
                const int row = r0 + rr;
                const int lx = row / 11, ly = row - lx * 11;
                const int gx = min(gx0 + lx, 127);
                const int gy = min(gy0 + ly, 127);
                const int z  = min(gz0 + zz, 127);
                const float* s = phi + (size_t)((gx * 128 + gy) * 128 + z) * 3;
                raw[rr * 36 + zz * 3 + 0] = s[0];
                raw[rr * 36 + zz * 3 + 1] = s[1];
                raw[rr * 36 + zz * 3 + 2] = s[2];
            }
        }
        __syncthreads();
        for (int p = threadIdx.x; p < nr * 24; p += 512) {
            const int rr = p / 24, t = p - rr * 24;
            const int s = t / 3, c = t - 3 * s;
            const float* r = &raw[rr * 36 + s * 3 + c];
            W4[(r0 + rr) * W4STRIDE + t] = make_float4(r[0], r[3], r[6], r[9]);
        }
        __syncthreads();
    }

    for (unsigned k = start + threadIdx.x; k < start + cnt; k += 512) {
        const float4 r4 = rec[k];
        const int idx = __float_as_int(r4.w);

        const float U = (r4.x + 1.0f) * 62.5f;
        const float V = (r4.y + 1.0f) * 62.5f;
        const float Z = (r4.z + 1.0f) * 62.5f;
        const float fu = floorf(U), fv = floorf(V), fw = floorf(Z);
        const int ix = (int)fu, iy = (int)fv, iz = (int)fw;
        const float u = U - fu, v = V - fv, w = Z - fw;

        float wu[4], wv[4], wz[4];
        bspline_w(u, wu[0], wu[1], wu[2], wu[3]);
        bspline_w(v, wv[0], wv[1], wv[2], wv[3]);
        bspline_w(w, wz[0], wz[1], wz[2], wz[3]);

        // z clamp via weight shift
        int izb = iz < 0 ? 0 : iz;
        const bool sh = izb > 124;
        if (sh) izb = 124;
        v2f zwLo, zwHi;
        zwLo.x = sh ? 0.0f : wz[0];
        zwLo.y = sh ? wz[0] : wz[1];
        zwHi.x = sh ? wz[1] : wz[2];
        zwHi.y = sh ? (wz[2] + wz[3]) : wz[3];
        const int lzb3 = (izb - gz0) * 3;

        int lxi[4], lyi[4];
#pragma unroll
        for (int l = 0; l < 4; ++l) {
            lxi[l] = min(max(ix + l, 0), 127) - gx0;
            lyi[l] = min(max(iy + l, 0), 127) - gy0;
        }

        v2f acc0 = {0.0f, 0.0f}, acc1 = {0.0f, 0.0f}, acc2 = {0.0f, 0.0f};
#pragma unroll
        for (int l = 0; l < 4; ++l) {
            const int rowx = lxi[l] * 11;
#pragma unroll
            for (int m = 0; m < 4; ++m) {
                const int base = (rowx + lyi[m]) * W4STRIDE + lzb3;
                const float4 a  = W4[base + 0];
                const float4 bb = W4[base + 1];
                const float4 cc = W4[base + 2];
                const float wm = wu[l] * wv[m];
                const v2f cLo = wm * zwLo;
                const v2f cHi = wm * zwHi;
                v2f aLo = {a.x, a.y},  aHi = {a.z, a.w};
                v2f bLo = {bb.x, bb.y}, bHi = {bb.z, bb.w};
                v2f gLo = {cc.x, cc.y}, gHi = {cc.z, cc.w};
                acc0 = __builtin_elementwise_fma(cLo, aLo, acc0);
                acc0 = __builtin_elementwise_fma(cHi, aHi, acc0);
                acc1 = __builtin_elementwise_fma(cLo, bLo, acc1);
                acc1 = __builtin_elementwise_fma(cHi, bHi, acc1);
                acc2 = __builtin_elementwise_fma(cLo, gLo, acc2);
                acc2 = __builtin_elementwise_fma(cHi, gHi, acc2);
            }
        }
        float* o = out + 3 * (size_t)idx;
        o[0] = acc0.x + acc0.y;
        o[1] = acc1.x + acc1.y;
        o[2] = acc2.x + acc2.y;
    }
}

// ---- fallback: direct kernel (ws too small) ----
__global__ __launch_bounds__(256) void bspline3d_direct(
    const float* __restrict__ xs, const float* __restrict__ ys,
    const float* __restrict__ zs, const float* __restrict__ phi,
    float* __restrict__ out, int n) {
    const int i = blockIdx.x * blockDim.x + threadIdx.x;
    if (i >= n) return;
    float u = (xs[i] + 1.0f) * 62.5f;
    float v = (ys[i] + 1.0f) * 62.5f;
    float w = (zs[i] + 1.0f) * 62.5f;
    const float fu = floorf(u), fv = floorf(v), fw = floorf(w);
    const int ix = (int)fu, iy = (int)fv, iz = (int)fw;
    u -= fu; v -= fv; w -= fw;
    float wu[4], wv[4], wz[4];
    bspline_w(u, wu[0], wu[1], wu[2], wu[3]);
    bspline_w(v, wv[0], wv[1], wv[2], wv[3]);
    bspline_w(w, wz[0], wz[1], wz[2], wz[3]);
    int izb = iz < 0 ? 0 : iz;
    const bool sh = izb > 124;
    if (sh) izb = 124;
    const float zw0 = sh ? 0.0f : wz[0];
    const float zw1 = sh ? wz[0] : wz[1];
    const float zw2 = sh ? wz[1] : wz[2];
    const float zw3 = sh ? (wz[2] + wz[3]) : wz[3];
    int xi[4], yi[4];
#pragma unroll
    for (int l = 0; l < 4; ++l) {
        xi[l] = min(max(ix + l, 0), 127);
        yi[l] = min(max(iy + l, 0), 127);
    }
    const float* pz = phi + izb * 3;
    float acc0 = 0.0f, acc1 = 0.0f, acc2 = 0.0f;
#pragma unroll
    for (int l = 0; l < 4; ++l) {
        const int rowx = xi[l] << 7;
#pragma unroll
        for (int m = 0; m < 4; ++m) {
            const float* p = pz + (rowx + yi[m]) * 384;
            const float4 a = *reinterpret_cast<const float4*>(p);
            const float4 b = *reinterpret_cast<const float4*>(p + 4);
            const float4 c = *reinterpret_cast<const float4*>(p + 8);
            const float wm = wu[l] * wv[m];
            const float c0 = wm * zw0, c1 = wm * zw1, c2 = wm * zw2, c3 = wm * zw3;
            acc0 = fmaf(c0, a.x, acc0); acc1 = fmaf(c0, a.y, acc1); acc2 = fmaf(c0, a.z, acc2);
            acc0 = fmaf(c1, a.w, acc0); acc1 = fmaf(c1, b.x, acc1); acc2 = fmaf(c1, b.y, acc2);
            acc0 = fmaf(c2, b.z, acc0); acc1 = fmaf(c2, b.w, acc1); acc2 = fmaf(c2, c.x, acc2);
            acc0 = fmaf(c3, c.y, acc0); acc1 = fmaf(c3, c.z, acc1); acc2 = fmaf(c3, c.w, acc2);
        }
    }
    float* o = out + 3 * (size_t)i;
    o[0] = acc0; o[1] = acc1; o[2] = acc2;
}

extern "C" void kernel_launch(void* const* d_in, const int* in_sizes, int n_in,
                              void* d_out, int out_size, void* d_ws,
                              size_t ws_size, hipStream_t stream) {
    const float* xs  = (const float*)d_in[0];
    const float* ys  = (const float*)d_in[1];
    const float* zs  = (const float*)d_in[2];
    const float* phi = (const float*)d_in[3];
    float* out = (float*)d_out;
    const int n = in_sizes[0];

    const size_t hist_off  = 0;                                    // u16[512][4096]
    const size_t total_off = hist_off + (size_t)NBLK * NBINS * 2;  // u32[4096]
    const size_t base_off  = total_off + NBINS * 4;                // u32[4096]
    const size_t rec_off   = base_off + NBINS * 4;                 // float4[n]
    const size_t need = rec_off + (size_t)n * 16;

    if (ws_size < need) {
        bspline3d_direct<<<(n + 255) / 256, 256, 0, stream>>>(xs, ys, zs, phi,
                                                              out, n);
        return;
    }

    unsigned short* hist = (unsigned short*)((char*)d_ws + hist_off);
    unsigned* total      = (unsigned*)((char*)d_ws + total_off);
    unsigned* binbase    = (unsigned*)((char*)d_ws + base_off);
    float4*   rec        = (float4*)((char*)d_ws + rec_off);

    // chunk multiple of 4 so vectorized loads stay 16B-aligned
    const int chunk = (((n + NBLK - 1) / NBLK) + 3) & ~3;

    hist_kernel<<<NBLK, 1024, 0, stream>>>(xs, ys, zs, hist, n, chunk);
    colscan_kernel<<<NBINS / 256, 256, 0, stream>>>(hist, total);
    scan_kernel<<<1, 1024, 0, stream>>>(total, binbase);
    scatter_kernel<<<NBLK, 1024, 0, stream>>>(xs, ys, zs, hist, binbase, rec,
                                              n, chunk);
    eval_kernel<<<NBINS, 512, 0, stream>>>(rec, binbase, total, phi, out);
}